// Round 9
// baseline (2111.757 us; speedup 1.0000x reference)
//
#include <hip/hip_runtime.h>

#define IMH 64
#define IMW 64
#define HWSZ 4096
#define BATCH 16
#define TSTEPS 16
#define PADW 66

typedef _Float16 half8 __attribute__((ext_vector_type(8)));
typedef _Float16 half4 __attribute__((ext_vector_type(4)));
typedef float floatx4 __attribute__((ext_vector_type(4)));
typedef int intx4 __attribute__((ext_vector_type(4)));

__device__ __forceinline__ float sigmoidf_(float x) { return 1.f / (1.f + __expf(-x)); }
__device__ __forceinline__ float tanhf_(float x) { return 1.f - 2.f / (1.f + __expf(2.f * x)); }

// Dense weight repack: wr[gt][m][k32], m = (g*4+hg)*16 + i, out = g*64+hg*16+i.
// kg = chunk*32+k ; xmode: kg<64 -> ci=kg+1 (h), kg==64 -> ci=0 (x), else zero-pad.
__global__ void repack_w(const float* __restrict__ w, _Float16* __restrict__ wr,
                         int ngt, int cin, int xmode) {
    int total = ngt * 8192;
    for (int idx = blockIdx.x * blockDim.x + threadIdx.x; idx < total;
         idx += gridDim.x * blockDim.x) {
        int k = idx & 31;
        int m = (idx >> 5) & 255;
        int gt = idx >> 13;
        int chunk = gt / 9, tap = gt - chunk * 9;
        int bidx = m >> 4, i = m & 15;
        int g = bidx >> 2, hg = bidx & 3;
        int out = g * 64 + hg * 16 + i;
        int kg = chunk * 32 + k;
        int ci = xmode ? (kg < 64 ? kg + 1 : (kg == 64 ? 0 : -1))
                       : (kg < cin ? kg : -1);
        float v = (ci >= 0) ? w[(out * cin + ci) * 9 + tap] : 0.f;
        wr[idx] = (_Float16)v;
    }
}

// Fused conv3x3 -> 4 gates -> LSTM update. f16 MFMA implicit GEMM.
// Block: 256 thr (4 waves = 4 hid-groups), ONE image row x 64 cols, wave tile 64x64.
// Weights direct from L1/L2 per tap (per-lane contiguous 16B). Act tile
// (3 halo rows x 66 cols x 32ch) DOUBLE-buffered in LDS, staged via register
// prefetch pf[] issued a full chunk ahead -> load latency hidden under 9 taps.
// ONE barrier per chunk: st(k) and taps(k-1) touch different buffers, so
// st -> barrier -> ld(k+1) -> taps(k) is race-free.
// LDS pixel stride 80B (4 data slots + 1 pad) -> 2-way bank access (free).
template<int NCHUNK, int XCHUNK>
__global__ __launch_bounds__(256, 3) void lstm_mfma_kernel(
    const _Float16* __restrict__ srcA,    // chunks 0-1 (padded pixel-major h)
    const _Float16* __restrict__ srcB,    // chunks 2-3
    const float* __restrict__ xsrc,       // layer0 x_t (batch stride TSTEPS*HWSZ)
    _Float16* __restrict__ hpad,          // out h [B][66][66][64]
    float* __restrict__ cpix,             // in-place c [B][4096][64]
    const _Float16* __restrict__ wr,      // [NGT][256][32] dense f16
    const float* __restrict__ bias)       // [256]
{
    __shared__ __align__(16) _Float16 act[2][198 * 5 * 8];  // 2 x 15.5 KB

    const int tid = threadIdx.x;
    const int lane = tid & 63;
    const int n = lane & 15, q = lane >> 4;
    const int hg = tid >> 6;                 // wave = hid group 0..3
    const int rb = blockIdx.x;               // image row 0..63
    const int b = blockIdx.y;

    floatx4 acc[4][4];
    #pragma unroll
    for (int g = 0; g < 4; ++g)
        #pragma unroll
        for (int i = 0; i < 4; ++i) acc[g][i] = (floatx4){0.f, 0.f, 0.f, 0.f};

    intx4 pf[4];                             // prefetched act tile pieces
    float xpf = 0.f;                         // prefetched x value (XCHUNK)

    // issue chunk's global loads into registers (no LDS access)
    auto ld = [&](int chunk) {
        if (chunk >= NCHUNK) return;
        if (chunk == XCHUNK) {
            if (tid < 198) {
                int r = tid / 66, cs = tid - r * 66;
                int gy = rb - 1 + r, gx = cs - 1;
                xpf = 0.f;
                if (gy >= 0 && gy < IMH && gx >= 0 && gx < IMW)
                    xpf = xsrc[(size_t)b * (TSTEPS * HWSZ) + gy * IMW + gx];
            }
            return;
        }
        const _Float16* buf = (chunk < 2) ? srcA : srcB;
        const int halfsel = chunk & 1;
        #pragma unroll
        for (int i = 0; i < 4; ++i) {
            int t = tid + i * 256;
            if (t < 792) {
                int pix = t >> 2, sl = t & 3;
                int r = pix / 66, cs = pix - r * 66;
                pf[i] = *(const intx4*)(buf
                    + ((size_t)(b * PADW + rb + r) * PADW + cs) * 64
                    + halfsel * 32 + sl * 8);
            }
        }
    };

    // commit prefetched registers to LDS buffer chunk&1
    auto st = [&](int chunk) {
        _Float16* dst = act[chunk & 1];
        if (chunk == XCHUNK) {
            if (tid < 198) {
                half8 hz;
                #pragma unroll
                for (int j = 0; j < 8; ++j) hz[j] = (_Float16)0.f;
                half8 h0 = hz;
                h0[0] = (_Float16)xpf;
                *(half8*)&dst[(tid * 5 + 0) * 8] = h0;
                *(half8*)&dst[(tid * 5 + 1) * 8] = hz;
                *(half8*)&dst[(tid * 5 + 2) * 8] = hz;
                *(half8*)&dst[(tid * 5 + 3) * 8] = hz;
            }
            return;
        }
        #pragma unroll
        for (int i = 0; i < 4; ++i) {
            int t = tid + i * 256;
            if (t < 792) {
                int pix = t >> 2, sl = t & 3;
                *(intx4*)&dst[(pix * 5 + sl) * 8] = pf[i];
            }
        }
    };

    ld(0);

    for (int chunk = 0; chunk < NCHUNK; ++chunk) {
        st(chunk);             // writes buf[chunk&1]; other waves may still read buf[1-..] (safe)
        __syncthreads();       // writes visible; all waves done with buf[chunk&1] readers (2 ago)
        ld(chunk + 1);         // global loads get the whole tap loop to complete
        const _Float16* ab = act[chunk & 1];
        const _Float16* wbase = wr + (size_t)(chunk * 9) * 8192 + (hg * 16 + n) * 32 + q * 8;
        #pragma unroll
        for (int tap = 0; tap < 9; ++tap) {
            half8 wfr[4];
            #pragma unroll
            for (int g = 0; g < 4; ++g)
                wfr[g] = *(const half8*)(wbase + (size_t)tap * 8192 + g * 2048);
            const int dy = tap / 3, dx = tap - dy * 3;
            half8 bfr[4];
            #pragma unroll
            for (int ni = 0; ni < 4; ++ni) {
                int col = 16 * ni + n + dx;              // 0..65
                bfr[ni] = *(const half8*)&ab[((dy * 66 + col) * 5 + q) * 8];
            }
            #pragma unroll
            for (int g = 0; g < 4; ++g)
                #pragma unroll
                for (int ni = 0; ni < 4; ++ni)
                    acc[g][ni] = __builtin_amdgcn_mfma_f32_16x16x32_f16(
                        wfr[g], bfr[ni], acc[g][ni], 0, 0, 0);
        }
    }

    // Epilogue: lane holds gates for h = hg*16+q*4+r, pixel row rb, col 16*ni+n
    const int hb = hg * 16 + q * 4;
    floatx4 bi = *(const floatx4*)&bias[hb];
    floatx4 bf = *(const floatx4*)&bias[64 + hb];
    floatx4 bo = *(const floatx4*)&bias[128 + hb];
    floatx4 bg = *(const floatx4*)&bias[192 + hb];
    #pragma unroll
    for (int ni = 0; ni < 4; ++ni) {
        int col = 16 * ni + n;
        size_t cidx = ((size_t)b * HWSZ + rb * IMW + col) * 64 + hb;
        floatx4 cold = *(const floatx4*)&cpix[cidx];
        floatx4 cnew;
        half4 hv;
        #pragma unroll
        for (int r = 0; r < 4; ++r) {
            float zi = acc[0][ni][r] + bi[r];
            float zf = acc[1][ni][r] + bf[r];
            float zo = acc[2][ni][r] + bo[r];
            float zg = acc[3][ni][r] + bg[r];
            float cn = fmaf(sigmoidf_(zf), cold[r], sigmoidf_(zi) * tanhf_(zg));
            cnew[r] = cn;
            hv[r] = (_Float16)(sigmoidf_(zo) * tanhf_(cn));
        }
        *(floatx4*)&cpix[cidx] = cnew;
        *(half4*)&hpad[((size_t)(b * PADW + rb + 1) * PADW + col + 1) * 64 + hb] = hv;
    }
}

__global__ void head_kernel(const _Float16* __restrict__ h1pad,
                            const float* __restrict__ wh,
                            const float* __restrict__ bh,
                            float* __restrict__ out) {
    int nn = blockIdx.x * blockDim.x + threadIdx.x;  // 0..65535
    int b = nn >> 12, pp = nn & 4095;
    int y = pp >> 6, xc = pp & 63;
    const _Float16* base = h1pad + ((size_t)(b * PADW + y + 1) * PADW + xc + 1) * 64;
    float s = bh[0];
    #pragma unroll
    for (int h0 = 0; h0 < 64; h0 += 8) {
        half8 hv = *(const half8*)&base[h0];
        #pragma unroll
        for (int j = 0; j < 8; ++j) s = fmaf((float)hv[j], wh[h0 + j], s);
    }
    out[nn] = fmaxf(s, 0.f);
}

extern "C" void kernel_launch(void* const* d_in, const int* in_sizes, int n_in,
                              void* d_out, int out_size, void* d_ws, size_t ws_size,
                              hipStream_t stream) {
    const float* x  = (const float*)d_in[0];
    const float* w0 = (const float*)d_in[1];
    const float* b0 = (const float*)d_in[2];
    const float* w1 = (const float*)d_in[3];
    const float* b1 = (const float*)d_in[4];
    const float* wh = (const float*)d_in[5];
    const float* bh = (const float*)d_in[6];
    float* out = (float*)d_out;

    const size_t HPAD = (size_t)BATCH * PADW * PADW * 64;  // 4,460,544 halves
    const size_t CBUF = (size_t)BATCH * HWSZ * 64;         // 4,194,304 floats
    _Float16* hp  = (_Float16*)d_ws;
    _Float16* h0a = hp;
    _Float16* h0b = hp + HPAD;
    _Float16* h1a = hp + 2 * HPAD;
    _Float16* h1b = hp + 3 * HPAD;
    float* cbase = (float*)(hp + 4 * HPAD);
    float* c0 = cbase;
    float* c1 = cbase + CBUF;
    _Float16* wr0 = (_Float16*)(cbase + 2 * CBUF);   // 27*8192 halves
    _Float16* wr1 = wr0 + (size_t)27 * 8192;         // 36*8192 halves

    // zero h buffers (borders must stay 0) and c buffers
    hipMemsetAsync(d_ws, 0, 4 * HPAD * sizeof(_Float16) + 2 * CBUF * sizeof(float), stream);
    repack_w<<<864, 256, 0, stream>>>(w0, wr0, 27, 65, 1);
    repack_w<<<1152, 256, 0, stream>>>(w1, wr1, 36, 128, 0);

    _Float16* h0buf[2] = {h0a, h0b};
    _Float16* h1buf[2] = {h1a, h1b};
    dim3 grid(64, BATCH), block(256);                // 1024 blocks = 4/CU
    for (int t = 0; t < TSTEPS; ++t) {
        int cur = t & 1, nxt = cur ^ 1;
        // layer0: chunks = [h0 ch0-31][h0 ch32-63][x + zeros]
        lstm_mfma_kernel<3, 2><<<grid, block, 0, stream>>>(
            h0buf[cur], (const _Float16*)nullptr, x + (size_t)t * HWSZ,
            h0buf[nxt], c0, wr0, b0);
        // layer1: chunks = [h0new 0-31][h0new 32-63][h1 0-31][h1 32-63]
        lstm_mfma_kernel<4, -1><<<grid, block, 0, stream>>>(
            h0buf[nxt], h1buf[cur], (const float*)nullptr,
            h1buf[nxt], c1, wr1, b1);
    }
    // t=15 wrote h1buf[0]
    head_kernel<<<256, 256, 0, stream>>>(h1buf[0], wh, bh, out);
}